// Round 17
// baseline (289.194 us; speedup 1.0000x reference)
//
#include <hip/hip_runtime.h>

#define NN 20000
#define DD 128
#define HH 128
#define G4 512
#define DEG 32
#define NG 1250    // groups of 16 nodes; one WAVE per group, barrier-free scan

typedef __attribute__((ext_vector_type(4))) float f32x4;
typedef __attribute__((ext_vector_type(8))) short s16x8;

#ifndef __has_builtin
#define __has_builtin(x) 0
#endif

// Builtin transcendentals ONLY (round-9 lesson: raw inline-asm v_exp/v_rcp bypasses
// the compiler's trans-use hazard handling -> numerical corruption).
static __device__ __forceinline__ float fexp2(float x){
#if __has_builtin(__builtin_amdgcn_exp2f)
  return __builtin_amdgcn_exp2f(x);
#else
  return exp2f(x);
#endif
}
static __device__ __forceinline__ float frcp(float x){
#if __has_builtin(__builtin_amdgcn_rcpf)
  return __builtin_amdgcn_rcpf(x);
#else
  return 1.f/x;
#endif
}

// packed f32x2 -> bf16x2 (RNE) — VOP3, no trans hazard; proven since round 1
static __device__ __forceinline__ unsigned cvt_pk_bf16(float lo, float hi){
  unsigned r;
  asm("v_cvt_pk_bf16_f32 %0, %1, %2" : "=v"(r) : "v"(lo), "v"(hi));
  return r;
}
static __device__ __forceinline__ s16x8 ld8bf(const float* __restrict__ p){
  f32x4 a = *(const f32x4*)p;
  f32x4 b = *(const f32x4*)(p+4);
  union{unsigned u[4]; s16x8 v;} z;
  z.u[0]=cvt_pk_bf16(a[0],a[1]);
  z.u[1]=cvt_pk_bf16(a[2],a[3]);
  z.u[2]=cvt_pk_bf16(b[0],b[1]);
  z.u[3]=cvt_pk_bf16(b[2],b[3]);
  return z.v;
}
// scaled variant: multiply by s before bf16 conversion (log2e pre-scaling)
static __device__ __forceinline__ s16x8 ld8bf_s(const float* __restrict__ p, float s){
  f32x4 a = *(const f32x4*)p;
  f32x4 b = *(const f32x4*)(p+4);
  union{unsigned u[4]; s16x8 v;} z;
  z.u[0]=cvt_pk_bf16(a[0]*s,a[1]*s);
  z.u[1]=cvt_pk_bf16(a[2]*s,a[3]*s);
  z.u[2]=cvt_pk_bf16(b[0]*s,b[1]*s);
  z.u[3]=cvt_pk_bf16(b[2]*s,b[3]*s);
  return z.v;
}
// bf16 packed in u32 -> f32 (bf16 in high 16 bits IS the f32 bit pattern)
static __device__ __forceinline__ float lo16f(unsigned u){
  union{unsigned x; float f;} v; v.x = u << 16; return v.f;
}
static __device__ __forceinline__ float hi16f(unsigned u){
  union{unsigned x; float f;} v; v.x = u & 0xffff0000u; return v.f;
}
#define NLOG2E -1.44269504f
#define TLOG2E  2.88539008f

// ---------------- Phase 1: Hp = (h @ W_ih^T + b_ih + b_hh) * S[gate], bf16 ----------------
// PERMUTED layout: element (n, gate g, dim d=16w+4hi+r) stored at n*512 + w*64 + hi*16 + g*4 + r.
// PRE-SCALED by S = {-log2e, -log2e, 2log2e, -log2e} per gate (acc feeds exp2 directly).
__global__ __launch_bounds__(512,2) void k_hp(
    const float* __restrict__ h, const float* __restrict__ W_ih,
    const float* __restrict__ b_ih, const float* __restrict__ b_hh,
    unsigned short* __restrict__ Hp)
{
  const int tid=threadIdx.x, w=tid>>6, lane=tid&63, lo=lane&15, hi=lane>>4;
  const float SC[4]={NLOG2E,NLOG2E,TLOG2E,NLOG2E};
  s16x8 A[4][4];
#pragma unroll
  for(int g=0;g<4;++g){
    const float* wr=W_ih+(size_t)(128*g+16*w+lo)*DD+8*hi;
#pragma unroll
    for(int c=0;c<4;++c) A[g][c]=ld8bf_s(wr+32*c, SC[g]);
  }
  f32x4 bb[4];
#pragma unroll
  for(int g=0;g<4;++g){
    const int gcb=128*g+16*w+4*hi;
    bb[g]=(*(const f32x4*)(b_ih+gcb) + *(const f32x4*)(b_hh+gcb))*SC[g];
  }
  const int nchunk = (blockIdx.x < 57) ? 2 : 1;
  for(int cc=0; cc<nchunk; ++cc){
    const int n0 = ((cc? 256+blockIdx.x : blockIdx.x))*64;
    f32x4 acc[4][4];
#pragma unroll
    for(int g=0;g<4;++g)
#pragma unroll
      for(int nt=0;nt<4;++nt) acc[g][nt]=(f32x4)0.f;
#pragma unroll
    for(int c=0;c<4;++c){
      s16x8 B[4];
#pragma unroll
      for(int nt=0;nt<4;++nt){
        int nd=n0+16*nt+lo; if(nd>=NN) nd=NN-1;
        B[nt]=ld8bf(h+(size_t)nd*DD+32*c+8*hi);
      }
#pragma unroll
      for(int g=0;g<4;++g)
#pragma unroll
        for(int nt=0;nt<4;++nt)
          acc[g][nt]=__builtin_amdgcn_mfma_f32_16x16x32_bf16(A[g][c],B[nt],acc[g][nt],0,0,0);
    }
#pragma unroll
    for(int nt=0;nt<4;++nt){
      int nd=n0+16*nt+lo;
      if(nd<NN){
        unsigned short* p = Hp + (size_t)nd*G4 + w*64 + hi*16;
        uint4 q0, q1;
        q0.x=cvt_pk_bf16(acc[0][nt][0]+bb[0][0], acc[0][nt][1]+bb[0][1]);
        q0.y=cvt_pk_bf16(acc[0][nt][2]+bb[0][2], acc[0][nt][3]+bb[0][3]);
        q0.z=cvt_pk_bf16(acc[1][nt][0]+bb[1][0], acc[1][nt][1]+bb[1][1]);
        q0.w=cvt_pk_bf16(acc[1][nt][2]+bb[1][2], acc[1][nt][3]+bb[1][3]);
        q1.x=cvt_pk_bf16(acc[2][nt][0]+bb[2][0], acc[2][nt][1]+bb[2][1]);
        q1.y=cvt_pk_bf16(acc[2][nt][2]+bb[2][2], acc[2][nt][3]+bb[2][3]);
        q1.z=cvt_pk_bf16(acc[3][nt][0]+bb[3][0], acc[3][nt][1]+bb[3][1]);
        q1.w=cvt_pk_bf16(acc[3][nt][2]+bb[3][2], acc[3][nt][3]+bb[3][3]);
        *(uint4*)p = q0;
        *(uint4*)(p+8) = q1;
      }
    }
  }
}

// ---------------- Phase 2: WAVE-AUTONOMOUS LSTM scan — zero barriers in the t-loop ----------
// r16 + two bit-exact scheduling fixes:
//  (A) MFMA j-order rotates tiles (tile=(j>>4)*4+(j&3), c=(j>>2)&3): same-accumulator
//      dep distance 1 -> 4 ops (~68 cy >= MFMA latency). Per-acc c-order still 0,1,2,3.
//  (B) cell computed STAGE-MAJOR across 16 independent elements (all ei, all ef, ...)
//      so trans latencies overlap (this compiler does not auto-interleave dependent
//      chains — same failure as r15's ds_read->MFMA).
__global__ __launch_bounds__(512,1) void k_scan(
    const float* __restrict__ h, const int* __restrict__ nbr,
    const float* __restrict__ W_hh, const unsigned short* __restrict__ Hp,
    const float* __restrict__ W_out, const float* __restrict__ b_out,
    float* __restrict__ out)
{
  extern __shared__ char smem[];             // 163840 B
  const int tid=threadIdx.x, w=tid>>6, lane=tid&63, lo=lane&15, hi=lane>>4;

  // ---- stage W_hh: thread tid stages row r=tid (prescaled, swizzled) ----
  {
    const int r=tid;
    const float s = ((r>>7)==2) ? TLOG2E : NLOG2E;
    const float* wr = W_hh + (size_t)r*HH;
    const int sw = (r&7)<<4;
#pragma unroll
    for(int j=0;j<16;++j){
      s16x8 v = ld8bf_s(wr + 8*j, s);
      *(s16x8*)(smem + ((r*256 + j*16) ^ sw)) = v;
    }
  }
  __syncthreads();

  const int grp = w*256 + blockIdx.x;
  if(grp >= NG) return;                      // idle waves exit (no later barriers)
  const int n0 = grp*16;

  const int swz=(lo&7)<<4;
  char* hreg = smem + 131072 + w*4096;       // this wave's h buffer (16 nodes x 128 dims bf16)
  const char* rdA[4]; const char* rdB[4];
#pragma unroll
  for(int c=0;c<4;++c){
    const int off = (lo*256 + 64*c + 16*hi) ^ swz;
    rdA[c] = smem + off;
    rdB[c] = hreg + off;
  }
  // zero h(-1)
#pragma unroll
  for(int i=0;i<4;++i){
    uint4 z4={0u,0u,0u,0u};
    *(uint4*)(hreg + lane*16 + i*1024) = z4;
  }

  float cst[32];                             // C-state (x 2log2e), index e+16*half
#pragma unroll
  for(int i=0;i<32;++i) cst[i]=0.f;

  const int* nbp = nbr + (size_t)(n0 + lo)*DEG;
  int idx_cur = nbp[0];

#pragma unroll 1
  for(int t=0;t<DEG;++t){
    int tn=(t+1<DEG)? t+1 : t;
    int idx_next = nbp[tn];
    // gather this step's Hp chunks: 8 x 32B per lane (layout matches k_hp natively)
    const char* gp = (const char*)Hp + (size_t)(unsigned)idx_cur*1024 + hi*32;
    uint4 q[16];
#pragma unroll
    for(int db=0;db<8;++db){
      q[2*db  ]=*(const uint4*)(gp + db*128);
      q[2*db+1]=*(const uint4*)(gp + db*128 + 16);
    }
    // B fragments: full h(t-1) (read BEFORE any h(t) writes)
    s16x8 B[4];
#pragma unroll
    for(int c=0;c<4;++c) B[c]=*(const s16x8*)(rdB[c]);

#pragma unroll
    for(int half=0;half<2;++half){
      // acc init from gather
      f32x4 acc[4][4];                       // [gate][dl]
#pragma unroll
      for(int dl=0;dl<4;++dl){
        const uint4& a=q[2*(dl+4*half)];
        const uint4& b=q[2*(dl+4*half)+1];
        acc[0][dl][0]=lo16f(a.x); acc[0][dl][1]=hi16f(a.x); acc[0][dl][2]=lo16f(a.y); acc[0][dl][3]=hi16f(a.y);
        acc[1][dl][0]=lo16f(a.z); acc[1][dl][1]=hi16f(a.z); acc[1][dl][2]=lo16f(a.w); acc[1][dl][3]=hi16f(a.w);
        acc[2][dl][0]=lo16f(b.x); acc[2][dl][1]=hi16f(b.x); acc[2][dl][2]=lo16f(b.y); acc[2][dl][3]=hi16f(b.y);
        acc[3][dl][0]=lo16f(b.z); acc[3][dl][1]=hi16f(b.z); acc[3][dl][2]=lo16f(b.w); acc[3][dl][3]=hi16f(b.w);
      }
      // ---- software-pipelined W_hh stream, tile-rotated for MFMA dep distance 4 ----
      // j: tb=j>>4, c=(j>>2)&3, tl=j&3; tile=tb*4+tl (g=tile>>2, dl=tile&3);
      // m = g*8 + dl + 4*half. Per-acc accumulation order is c=0,1,2,3 (bit-exact).
#define TILEOF(J) ((((J)>>4)<<2) | ((J)&3))
#define AFADDR(J) (rdA[((J)>>2)&3] + ((((TILEOF(J)>>2)<<3) + (TILEOF(J)&3) + 4*half)*4096))
      s16x8 Afb[8];
#pragma unroll
      for(int j=0;j<8;++j) Afb[j]=*(const s16x8*)AFADDR(j);
#pragma unroll
      for(int j=0;j<64;++j){
        const int tile=TILEOF(j), g=tile>>2, dl=tile&3;
        acc[g][dl]=__builtin_amdgcn_mfma_f32_16x16x32_bf16(Afb[j&7],B[(j>>2)&3],acc[g][dl],0,0,0);
        if(j+8<64) Afb[j&7]=*(const s16x8*)AFADDR(j+8);
      }
#undef AFADDR
#undef TILEOF
      // ---- STAGE-MAJOR lane-local cell (bit-exact per-elem op sequence vs r16) ----
      // elem e = dl*4+r (dl=e>>2, r=e&3); cst index = e + 16*half.
      {
        float ei[16],ef[16],eg[16],eo[16],ec[16],hv[16];
#pragma unroll
        for(int e=0;e<16;++e) ei[e]=fexp2(acc[0][e>>2][e&3]);
#pragma unroll
        for(int e=0;e<16;++e) ef[e]=fexp2(acc[1][e>>2][e&3]);
#pragma unroll
        for(int e=0;e<16;++e) eg[e]=fexp2(acc[2][e>>2][e&3]);
#pragma unroll
        for(int e=0;e<16;++e) eo[e]=fexp2(acc[3][e>>2][e&3]);
#pragma unroll
        for(int e=0;e<16;++e){
          float itgT=__builtin_fmaf(eg[e], TLOG2E, -TLOG2E)*frcp((1.f+ei[e])*(1.f+eg[e]));
          float Cn=__builtin_fmaf(cst[e+16*half], frcp(1.f+ef[e]), itgT);
          cst[e+16*half]=Cn;
          ec[e]=fexp2(Cn);
        }
#pragma unroll
        for(int e=0;e<16;++e)
          hv[e]=(ec[e]-1.f)*frcp((1.f+eo[e])*(1.f+ec[e]));
#pragma unroll
        for(int dl=0;dl<4;++dl){
          const int db = dl + 4*half;
          uint2 pk;
          pk.x=cvt_pk_bf16(hv[dl*4+0],hv[dl*4+1]);
          pk.y=cvt_pk_bf16(hv[dl*4+2],hv[dl*4+3]);
          *(uint2*)(hreg + ((lo*256 + 32*db + 8*hi) ^ swz)) = pk;
        }
      }
    }
    idx_cur = idx_next;
  }

  // ---- fused output projection: out = relu([h, agg] @ W_out^T + b_out) ----
  s16x8 BB[8];
#pragma unroll
  for(int c=0;c<4;++c) BB[c]=ld8bf(h + (size_t)(n0+lo)*DD + 32*c + 8*hi);
#pragma unroll
  for(int c=0;c<4;++c) BB[4+c]=*(const s16x8*)(rdB[c]);
  f32x4 po[8];
#pragma unroll
  for(int m=0;m<8;++m) po[m]=(f32x4)0.f;
#pragma unroll
  for(int m=0;m<8;++m)
#pragma unroll
    for(int c=0;c<8;++c){
      s16x8 Af=ld8bf(W_out + (size_t)(16*m+lo)*256 + 32*c + 8*hi);
      po[m]=__builtin_amdgcn_mfma_f32_16x16x32_bf16(Af,BB[c],po[m],0,0,0);
    }
#pragma unroll
  for(int m=0;m<8;++m){
    f32x4 bias=*(const f32x4*)(b_out + 16*m + 4*hi);
#pragma unroll
    for(int r=0;r<4;++r){ float v=po[m][r]+bias[r]; po[m][r]=v>0.f?v:0.f; }
    *(f32x4*)(out + (size_t)(n0+lo)*HH + 16*m + 4*hi)=po[m];
  }
}

extern "C" void kernel_launch(void* const* d_in, const int* in_sizes, int n_in,
                              void* d_out, int out_size, void* d_ws, size_t ws_size,
                              hipStream_t stream)
{
  const float* h     = (const float*)d_in[0];
  const int*   nbr   = (const int*)d_in[1];
  const float* W_ih  = (const float*)d_in[2];
  const float* W_hh  = (const float*)d_in[3];
  const float* b_ih  = (const float*)d_in[4];
  const float* b_hh  = (const float*)d_in[5];
  const float* W_out = (const float*)d_in[6];
  const float* b_out = (const float*)d_in[7];
  unsigned short* Hp = (unsigned short*)d_ws;   // 20000*512*2B = 20.48 MB

  k_hp<<<256, 512, 0, stream>>>(h, W_ih, b_ih, b_hh, Hp);
  k_scan<<<256, 512, 163840, stream>>>(h, nbr, W_hh, Hp, W_out, b_out, (float*)d_out);
}

// Round 18
// 205.980 us; speedup vs baseline: 1.4040x; 1.4040x over previous
//
#include <hip/hip_runtime.h>

#define NN 20000
#define DD 128
#define HH 128
#define G4 512
#define DEG 32
#define NPB 32     // nodes per pair (2 staggered groups of 16)
#define PAIRS 625  // NN/NPB
#define GRID2 512  // k_lstm grid: exactly 2 blocks/CU resident; extra pairs work-stolen

typedef __attribute__((ext_vector_type(4))) float f32x4;
typedef __attribute__((ext_vector_type(8))) short s16x8;

#ifndef __has_builtin
#define __has_builtin(x) 0
#endif

__device__ int g_cnt;   // next pair index for work stealing; re-armed by k_hp each launch

// Builtin transcendentals ONLY (round-9 lesson: raw inline-asm v_exp/v_rcp bypasses
// the compiler's trans-use hazard handling -> numerical corruption).
static __device__ __forceinline__ float fexp2(float x){
#if __has_builtin(__builtin_amdgcn_exp2f)
  return __builtin_amdgcn_exp2f(x);
#else
  return exp2f(x);
#endif
}
static __device__ __forceinline__ float frcp(float x){
#if __has_builtin(__builtin_amdgcn_rcpf)
  return __builtin_amdgcn_rcpf(x);
#else
  return 1.f/x;
#endif
}

// packed f32x2 -> bf16x2 (RNE) — VOP3, no trans hazard; proven since round 1
static __device__ __forceinline__ unsigned cvt_pk_bf16(float lo, float hi){
  unsigned r;
  asm("v_cvt_pk_bf16_f32 %0, %1, %2" : "=v"(r) : "v"(lo), "v"(hi));
  return r;
}
static __device__ __forceinline__ s16x8 ld8bf(const float* __restrict__ p){
  f32x4 a = *(const f32x4*)p;
  f32x4 b = *(const f32x4*)(p+4);
  union{unsigned u[4]; s16x8 v;} z;
  z.u[0]=cvt_pk_bf16(a[0],a[1]);
  z.u[1]=cvt_pk_bf16(a[2],a[3]);
  z.u[2]=cvt_pk_bf16(b[0],b[1]);
  z.u[3]=cvt_pk_bf16(b[2],b[3]);
  return z.v;
}
// scaled variant: multiply by s before bf16 conversion (log2e pre-scaling)
static __device__ __forceinline__ s16x8 ld8bf_s(const float* __restrict__ p, float s){
  f32x4 a = *(const f32x4*)p;
  f32x4 b = *(const f32x4*)(p+4);
  union{unsigned u[4]; s16x8 v;} z;
  z.u[0]=cvt_pk_bf16(a[0]*s,a[1]*s);
  z.u[1]=cvt_pk_bf16(a[2]*s,a[3]*s);
  z.u[2]=cvt_pk_bf16(b[0]*s,b[1]*s);
  z.u[3]=cvt_pk_bf16(b[2]*s,b[3]*s);
  return z.v;
}
// bf16 packed in u32 -> f32 (bf16 in high 16 bits IS the f32 bit pattern)
static __device__ __forceinline__ float lo16f(unsigned u){
  union{unsigned x; float f;} v; v.x = u << 16; return v.f;
}
static __device__ __forceinline__ float hi16f(unsigned u){
  union{unsigned x; float f;} v; v.x = u & 0xffff0000u; return v.f;
}
#define NLOG2E -1.44269504f
#define TLOG2E  2.88539008f

// ---------------- Phase 1: Hp = (h @ W_ih^T + b_ih + b_hh) * S[gate], bf16 ----------------
// PERMUTED layout: element (n, gatecol=128g+16w+4hi+r) stored at n*512 + w*64 + hi*16 + g*4 + r.
// PRE-SCALED by S = {-log2e, -log2e, 2log2e, -log2e} per gate so the LSTM cell feeds
// the MFMA accumulator straight into exp2 with no argument multiply (shorter dep chain).
__global__ __launch_bounds__(512,2) void k_hp(
    const float* __restrict__ h, const float* __restrict__ W_ih,
    const float* __restrict__ b_ih, const float* __restrict__ b_hh,
    unsigned short* __restrict__ Hp)
{
  if(blockIdx.x==0 && threadIdx.x==0) g_cnt = GRID2;  // arm the k_lstm work-steal counter
  const int tid=threadIdx.x, w=tid>>6, lane=tid&63, lo=lane&15, hi=lane>>4;
  const float SC[4]={NLOG2E,NLOG2E,TLOG2E,NLOG2E};
  s16x8 A[4][4];
#pragma unroll
  for(int g=0;g<4;++g){
    const float* wr=W_ih+(size_t)(128*g+16*w+lo)*DD+8*hi;
#pragma unroll
    for(int c=0;c<4;++c) A[g][c]=ld8bf_s(wr+32*c, SC[g]);
  }
  f32x4 bb[4];
#pragma unroll
  for(int g=0;g<4;++g){
    const int gcb=128*g+16*w+4*hi;
    bb[g]=(*(const f32x4*)(b_ih+gcb) + *(const f32x4*)(b_hh+gcb))*SC[g];
  }
  // grid 256, blocks 0..56 take a second 64-node chunk (313 chunks total)
  const int nchunk = (blockIdx.x < 57) ? 2 : 1;
  for(int cc=0; cc<nchunk; ++cc){
    const int n0 = ((cc? 256+blockIdx.x : blockIdx.x))*64;
    f32x4 acc[4][4];
#pragma unroll
    for(int g=0;g<4;++g)
#pragma unroll
      for(int nt=0;nt<4;++nt) acc[g][nt]=(f32x4)0.f;
#pragma unroll
    for(int c=0;c<4;++c){
      s16x8 B[4];
#pragma unroll
      for(int nt=0;nt<4;++nt){
        int nd=n0+16*nt+lo; if(nd>=NN) nd=NN-1;
        B[nt]=ld8bf(h+(size_t)nd*DD+32*c+8*hi);
      }
#pragma unroll
      for(int g=0;g<4;++g)
#pragma unroll
        for(int nt=0;nt<4;++nt)
          acc[g][nt]=__builtin_amdgcn_mfma_f32_16x16x32_bf16(A[g][c],B[nt],acc[g][nt],0,0,0);
    }
#pragma unroll
    for(int nt=0;nt<4;++nt){
      int nd=n0+16*nt+lo;
      if(nd<NN){
        unsigned short* p = Hp + (size_t)nd*G4 + w*64 + hi*16;
        uint4 q0, q1;
        q0.x=cvt_pk_bf16(acc[0][nt][0]+bb[0][0], acc[0][nt][1]+bb[0][1]);
        q0.y=cvt_pk_bf16(acc[0][nt][2]+bb[0][2], acc[0][nt][3]+bb[0][3]);
        q0.z=cvt_pk_bf16(acc[1][nt][0]+bb[1][0], acc[1][nt][1]+bb[1][1]);
        q0.w=cvt_pk_bf16(acc[1][nt][2]+bb[1][2], acc[1][nt][3]+bb[1][3]);
        q1.x=cvt_pk_bf16(acc[2][nt][0]+bb[2][0], acc[2][nt][1]+bb[2][1]);
        q1.y=cvt_pk_bf16(acc[2][nt][2]+bb[2][2], acc[2][nt][3]+bb[2][3]);
        q1.z=cvt_pk_bf16(acc[3][nt][0]+bb[3][0], acc[3][nt][1]+bb[3][1]);
        q1.w=cvt_pk_bf16(acc[3][nt][2]+bb[3][2], acc[3][nt][3]+bb[3][3]);
        *(uint4*)p = q0;
        *(uint4*)(p+8) = q1;
      }
    }
  }
}

// unpack one lane's 32B Hp chunk into the 4-gate accumulator init
static __device__ __forceinline__ void unpack_acc(const uint4 q[2], f32x4 acc[4]){
  acc[0][0]=lo16f(q[0].x); acc[0][1]=hi16f(q[0].x); acc[0][2]=lo16f(q[0].y); acc[0][3]=hi16f(q[0].y);
  acc[1][0]=lo16f(q[0].z); acc[1][1]=hi16f(q[0].z); acc[1][2]=lo16f(q[0].w); acc[1][3]=hi16f(q[0].w);
  acc[2][0]=lo16f(q[1].x); acc[2][1]=hi16f(q[1].x); acc[2][2]=lo16f(q[1].y); acc[2][3]=hi16f(q[1].y);
  acc[3][0]=lo16f(q[1].z); acc[3][1]=hi16f(q[1].z); acc[3][2]=lo16f(q[1].w); acc[3][3]=hi16f(q[1].w);
}

// LSTM cell, log2-domain prescaled gates, T-domain cell state C = c*2log2e.
//   ei=2^acc_i = e^-i (prescale), eg = e^{2g}, etc.
//   itgT = sig(i)*tanh(g)*2log2e = fma(eg,T,-T) * rcp((1+ei)(1+eg))
//   C    = fma(C_old, rcp(1+ef), itgT)        // = c_new*2log2e
//   hv   = (2^C - 1) * rcp((1+eo)(1+2^C))     // sig(o)*tanh(c)
static __device__ __forceinline__ void cell_update(const f32x4 acc[4], float C[4],
                                                   char* wb, int waddr){
  float hv[4];
#pragma unroll
  for(int r=0;r<4;++r){
    float ei=fexp2(acc[0][r]);
    float ef=fexp2(acc[1][r]);
    float eg=fexp2(acc[2][r]);
    float eo=fexp2(acc[3][r]);
    float itgT=__builtin_fmaf(eg, TLOG2E, -TLOG2E)*frcp((1.f+ei)*(1.f+eg));
    float Cn=__builtin_fmaf(C[r], frcp(1.f+ef), itgT);
    C[r]=Cn;
    float ec=fexp2(Cn);
    hv[r]=(ec-1.f)*frcp((1.f+eo)*(1.f+ec));
  }
  uint2 pk;
  pk.x=cvt_pk_bf16(hv[0],hv[1]);
  pk.y=cvt_pk_bf16(hv[2],hv[3]);
  *(uint2*)(wb + waddr) = pk;
}

// ---------------- Phase 2: LSTM scan, staggered pipeline, work-stealing, t-unrolled x2 -----
// Grid = 512 (2 blocks/CU). Gather double-buffers statically renamed (use at i+2 intervals).
__global__ __launch_bounds__(512,2) void k_lstm(
    const float* __restrict__ h, const int* __restrict__ nbr,
    const float* __restrict__ W_hh, const unsigned short* __restrict__ Hp,
    const float* __restrict__ W_out, const float* __restrict__ b_out,
    float* __restrict__ out)
{
  __shared__ unsigned short hpA[16*HH];      // 4 KB
  __shared__ unsigned short hpB[16*HH];      // 4 KB
  __shared__ int nlds[DEG*NPB];              // transposed: nlds[t][node] = node_idx*G4, 4 KB
  __shared__ int spair;
  const int tid=threadIdx.x, w=tid>>6, lane=tid&63, lo=lane&15, hi=lane>>4;
  const int swz=(lo&7)<<4;
  const int woff=w*64+hi*16;                 // lane's Hp chunk offset (shorts)
  const int waddr=((lo*256 + 32*w + 8*hi) ^ swz);
  const float SC[4]={NLOG2E,NLOG2E,TLOG2E,NLOG2E};

  s16x8 A[4][4];                             // W_hh fragments (prescaled), pair-invariant
#pragma unroll
  for(int g=0;g<4;++g){
    const float* wr=W_hh+(size_t)(128*g+16*w+lo)*HH+8*hi;
#pragma unroll
    for(int c=0;c<4;++c) A[g][c]=ld8bf_s(wr+32*c, SC[g]);
  }

  int pair = blockIdx.x;
  for(;;){
    const int n0 = pair*NPB;
    {
      unsigned* za=(unsigned*)&hpA[0];
      unsigned* zb=(unsigned*)&hpB[0];
      za[tid]=0u; za[tid+512]=0u;            // zero hpA (h0 = 0)
      zb[tid]=0u; zb[tid+512]=0u;            // zero hpB
#pragma unroll
      for(int i=0;i<2;++i){                  // stage neighbor offsets transposed, pre-scaled
        int idx=tid+512*i;
        nlds[(idx&31)*NPB + (idx>>5)] = nbr[n0*DEG + idx]*G4;
      }
    }
    __syncthreads();

    float cstA[4]={0.f,0.f,0.f,0.f}, cstB[4]={0.f,0.f,0.f,0.f};  // C-state (x 2log2e)
    // accB(-1)=0 makes the first cellB produce h=0, C=0: exactly h_B(-1).
    f32x4 accA[4], accB[4];
#pragma unroll
    for(int g=0;g<4;++g) accB[g]=(f32x4)0.f;

    // gather double-buffers (statically renamed, no copies)
    uint4 qAx[2], qAy[2], qBx[2], qBy[2];
    {
      const unsigned short* ga=Hp+(size_t)nlds[lo]+woff;
      const unsigned short* gb=Hp+(size_t)nlds[16+lo]+woff;
      qAx[0]=*(const uint4*)ga; qAx[1]=*(const uint4*)(ga+8);
      qBx[0]=*(const uint4*)gb; qBx[1]=*(const uint4*)(gb+8);
    }

#define INTERVAL_P(QUSE, QLOAD, TLOAD) { \
      { const unsigned short* gp_=Hp+(size_t)nlds[(TLOAD)*NPB+lo]+woff; \
        QLOAD[0]=*(const uint4*)gp_; QLOAD[1]=*(const uint4*)(gp_+8); } \
      s16x8 Ba[4]; \
      const char* ra=(const char*)&hpA[0]; \
      _Pragma("unroll") \
      for(int c=0;c<4;++c) Ba[c]=*(const s16x8*)(ra + (((lo*256 + 64*c + 16*hi)) ^ swz)); \
      cell_update(accB, cstB, (char*)&hpB[0], waddr); \
      unpack_acc(QUSE, accA); \
      _Pragma("unroll") \
      for(int c=0;c<4;++c) \
        _Pragma("unroll") \
        for(int g=0;g<4;++g) \
          accA[g]=__builtin_amdgcn_mfma_f32_16x16x32_bf16(A[g][c],Ba[c],accA[g],0,0,0); \
      asm volatile("s_waitcnt lgkmcnt(0)\n\ts_barrier" ::: "memory"); }

#define INTERVAL_Q(QUSE, QLOAD, TLOAD) { \
      { const unsigned short* gp_=Hp+(size_t)nlds[(TLOAD)*NPB+16+lo]+woff; \
        QLOAD[0]=*(const uint4*)gp_; QLOAD[1]=*(const uint4*)(gp_+8); } \
      s16x8 Bb[4]; \
      const char* rb=(const char*)&hpB[0]; \
      _Pragma("unroll") \
      for(int c=0;c<4;++c) Bb[c]=*(const s16x8*)(rb + (((lo*256 + 64*c + 16*hi)) ^ swz)); \
      cell_update(accA, cstA, (char*)&hpA[0], waddr); \
      unpack_acc(QUSE, accB); \
      _Pragma("unroll") \
      for(int c=0;c<4;++c) \
        _Pragma("unroll") \
        for(int g=0;g<4;++g) \
          accB[g]=__builtin_amdgcn_mfma_f32_16x16x32_bf16(A[g][c],Bb[c],accB[g],0,0,0); \
      asm volatile("s_waitcnt lgkmcnt(0)\n\ts_barrier" ::: "memory"); }

    for(int k=0;k<DEG/2;++k){
      const int t1=2*k+1;
      const int t2 = (t1+1<DEG)? t1+1 : t1;  // clamp: last dummy load re-reads t=31
      // t even: use x-buffers, load y-buffers (for t1)
      INTERVAL_P(qAx, qAy, t1)
      INTERVAL_Q(qBx, qBy, t1)
      // t odd: use y-buffers, load x-buffers (for t2)
      INTERVAL_P(qAy, qAx, t2)
      INTERVAL_Q(qBy, qBx, t2)
    }
#undef INTERVAL_P
#undef INTERVAL_Q

    // drain: cell for group B at t=31 -> hpB holds h_B(31)
    cell_update(accB, cstB, (char*)&hpB[0], waddr);
    asm volatile("s_waitcnt lgkmcnt(0)\n\ts_barrier" ::: "memory");

    // ---- fused output projection: out = relu([h, agg] @ W_out^T + b_out) ----
    s16x8 AO[8];
    {
      const float* wr=W_out+(size_t)(16*w+lo)*256+8*hi;
#pragma unroll
      for(int c=0;c<8;++c) AO[c]=ld8bf(wr+32*c);
    }
    const int ob=16*w+4*hi;
    f32x4 bias=*(const f32x4*)(b_out+ob);
#pragma unroll
    for(int nt=0;nt<2;++nt){
      const int node=n0+nt*16+lo;
      s16x8 BB[8];
      const float* hr=h+(size_t)node*DD+8*hi;
#pragma unroll
      for(int c=0;c<4;++c) BB[c]=ld8bf(hr+32*c);
      const char* rb=(const char*)(nt? &hpB[0] : &hpA[0]);
#pragma unroll
      for(int c=0;c<4;++c)
        BB[4+c]=*(const s16x8*)(rb + (((lo*256 + 64*c + 16*hi)) ^ swz));
      f32x4 acc=(f32x4)0.f;
#pragma unroll
      for(int c=0;c<8;++c) acc=__builtin_amdgcn_mfma_f32_16x16x32_bf16(AO[c],BB[c],acc,0,0,0);
#pragma unroll
      for(int r=0;r<4;++r){ float v=acc[r]+bias[r]; acc[r]=v>0.f?v:0.f; }
      *(f32x4*)(out+(size_t)node*HH+ob)=acc;
    }

    // ---- steal the next pair; barrier also protects LDS reuse across pairs ----
    if(tid==0) spair = atomicAdd(&g_cnt, 1);
    __syncthreads();
    pair = spair;
    if(pair >= PAIRS) break;
  }
}

extern "C" void kernel_launch(void* const* d_in, const int* in_sizes, int n_in,
                              void* d_out, int out_size, void* d_ws, size_t ws_size,
                              hipStream_t stream)
{
  const float* h     = (const float*)d_in[0];
  const int*   nbr   = (const int*)d_in[1];
  const float* W_ih  = (const float*)d_in[2];
  const float* W_hh  = (const float*)d_in[3];
  const float* b_ih  = (const float*)d_in[4];
  const float* b_hh  = (const float*)d_in[5];
  const float* W_out = (const float*)d_in[6];
  const float* b_out = (const float*)d_in[7];
  unsigned short* Hp = (unsigned short*)d_ws;   // 20000*512*2B = 20.48 MB

  k_hp<<<256, 512, 0, stream>>>(h, W_ih, b_ih, b_hh, Hp);
  k_lstm<<<GRID2, 512, 0, stream>>>(h, nbr, W_hh, Hp, W_out, b_out, (float*)d_out);
}